// Round 9
// baseline (948.867 us; speedup 1.0000x reference)
//
#include <hip/hip_runtime.h>
#include <hip/hip_bf16.h>
#include <math.h>

#define NPOS 16384   // B*H*W = 16*32*32
#define DD   512
#define PP   ((size_t)NPOS * DD)   // 8388608 elements per plane

typedef __bf16 bf16x8 __attribute__((ext_vector_type(8)));
typedef __bf16 bf16x4 __attribute__((ext_vector_type(4)));
typedef float  f32x4  __attribute__((ext_vector_type(4)));

// async global->LDS, 16 B per lane; LDS dest = wave-uniform base + lane*16
__device__ __forceinline__ void g2lds16(const void* g, void* l) {
  __builtin_amdgcn_global_load_lds(
      (__attribute__((address_space(1))) void*)g,
      (__attribute__((address_space(3))) void*)l, 16, 0, 0);
}

// ================= bf16 MFMA GEMM, double-buffered LDS =================
// C = A(MxK) @ Bt^T + bias.  A: MxK bf16 (ld K). Bt: NxK bf16 (ld K).
// epi 0: C0 fp32 (ld N) = acc + bias
// epi 1: N=1024; cols<512 -> C0 fp32 (ld 512); cols>=512 -> sigmoid -> C1 bf16 (ld 512)
// epi 2: C0 fp32 (ld N) = acc + bias + res
__global__ __launch_bounds__(256, 3) void gemm_bf_k(
    const __bf16* __restrict__ A, const __bf16* __restrict__ Bt,
    const float* __restrict__ bias, const float* __restrict__ res,
    float* __restrict__ C0, __bf16* __restrict__ C1,
    int N, int K, int epi)
{
  __shared__ __bf16 Asm[2][128 * 32];
  __shared__ __bf16 Bsm[2][128 * 32];
  const int tid  = threadIdx.x;
  const int wave = tid >> 6;
  const int lane = tid & 63;
  const int quad = lane >> 4;
  const int l16  = lane & 15;
  const int bm = blockIdx.y * 128;
  const int bn = blockIdx.x * 128;
  const int wm = (wave >> 1) << 6;
  const int wn = (wave & 1) << 6;

  const int srow   = lane >> 2;                                  // row within 16-row stage
  const int schunk = (((lane & 3) ^ ((lane >> 3) & 3)) << 3);    // swizzled k-chunk (elements)

  f32x4 acc[4][4];
  const f32x4 z4 = {0.f, 0.f, 0.f, 0.f};
  #pragma unroll
  for (int i = 0; i < 4; ++i)
    #pragma unroll
    for (int j = 0; j < 4; ++j) acc[i][j] = z4;

  const __bf16* Ab = A  + (size_t)bm * K;
  const __bf16* Bb = Bt + (size_t)bn * K;
  const int nk = K >> 5;

  #define STAGE(buf, kb)                                                              \
    {                                                                                 \
      const int k0s = (kb) << 5;                                                      \
      _Pragma("unroll")                                                               \
      for (int c = 0; c < 2; ++c) {                                                   \
        const int cc = wave * 2 + c;                                                  \
        g2lds16(Ab + (size_t)(cc * 16 + srow) * K + k0s + schunk, &Asm[buf][cc * 512]);\
        g2lds16(Bb + (size_t)(cc * 16 + srow) * K + k0s + schunk, &Bsm[buf][cc * 512]);\
      }                                                                               \
    }

  STAGE(0, 0)
  int cur = 0;
  for (int kb = 0; kb < nk; ++kb) {
    __syncthreads();
    if (kb + 1 < nk) STAGE(cur ^ 1, kb + 1)
    bf16x8 af[4], bg[4];
    #pragma unroll
    for (int i = 0; i < 4; ++i) {
      int m = wm + i * 16 + l16;
      af[i] = *(const bf16x8*)(&Asm[cur][m * 32 + ((quad ^ ((m >> 1) & 3)) << 3)]);
    }
    #pragma unroll
    for (int j = 0; j < 4; ++j) {
      int n = wn + j * 16 + l16;
      bg[j] = *(const bf16x8*)(&Bsm[cur][n * 32 + ((quad ^ ((n >> 1) & 3)) << 3)]);
    }
    #pragma unroll
    for (int i = 0; i < 4; ++i)
      #pragma unroll
      for (int j = 0; j < 4; ++j)
        acc[i][j] = __builtin_amdgcn_mfma_f32_16x16x32_bf16(af[i], bg[j], acc[i][j], 0, 0, 0);
    cur ^= 1;
  }
  #undef STAGE

  // epilogue. C/D layout: col = lane&15, row = quad*4 + reg  [m89-verified]
  const bool dosig = (epi == 1) && (bn >= 512);
  #pragma unroll
  for (int j = 0; j < 4; ++j) {
    const int col = wn + j * 16 + l16;
    const float bv = bias[bn + col];
    #pragma unroll
    for (int i = 0; i < 4; ++i) {
      const int row0 = bm + wm + i * 16 + quad * 4;
      #pragma unroll
      for (int r = 0; r < 4; ++r) {
        float v = acc[i][j][r] + bv;
        if (epi == 1) {
          if (dosig) {
            v = 1.f / (1.f + expf(-v));
            C1[(size_t)(row0 + r) * 512 + (bn - 512) + col] = (__bf16)v;
          } else {
            C0[(size_t)(row0 + r) * 512 + bn + col] = v;
          }
        } else {
          size_t off = (size_t)(row0 + r) * N + bn + col;
          if (epi == 2) v += res[off];
          C0[off] = v;
        }
      }
    }
  }
}

// ---------------- fp32 -> bf16 elementwise (tokens) ----------------
__global__ __launch_bounds__(256) void cvt_k(const float* __restrict__ s, __bf16* __restrict__ d)
{
  size_t i = ((size_t)blockIdx.x * 256 + threadIdx.x) * 8;
  float4 a = *(const float4*)(s + i);
  float4 b = *(const float4*)(s + i + 4);
  bf16x8 v;
  v[0] = (__bf16)a.x; v[1] = (__bf16)a.y; v[2] = (__bf16)a.z; v[3] = (__bf16)a.w;
  v[4] = (__bf16)b.x; v[5] = (__bf16)b.y; v[6] = (__bf16)b.z; v[7] = (__bf16)b.w;
  *(bf16x8*)(d + i) = v;
}

// ---------------- transpose KxN fp32 -> NxK bf16 (weights) ----------------
__global__ __launch_bounds__(256) void tr_k(const float* __restrict__ src, __bf16* __restrict__ dst,
                                            int K, int N, size_t sstr, size_t dstr)
{
  __shared__ float t[32][33];
  const float* s = src + blockIdx.z * sstr;
  __bf16* d = dst + blockIdx.z * dstr;
  int n0 = blockIdx.x * 32, k0 = blockIdx.y * 32;
  int tx = threadIdx.x & 31, ty = threadIdx.x >> 5;   // 32x8
  #pragma unroll
  for (int i = 0; i < 4; ++i)
    t[ty + i * 8][tx] = s[(size_t)(k0 + ty + i * 8) * N + n0 + tx];
  __syncthreads();
  #pragma unroll
  for (int i = 0; i < 4; ++i)
    d[(size_t)(n0 + ty + i * 8) * K + k0 + tx] = (__bf16)t[tx][ty + i * 8];
}

// ---------------- LayerNorm over D=512, one wave per position, bf16 out ----------------
__global__ __launch_bounds__(256) void ln_k(const float* __restrict__ x, const float* __restrict__ w,
                                            const float* __restrict__ bv, __bf16* __restrict__ out)
{
  int gw = (blockIdx.x * 256 + threadIdx.x) >> 6;   // position
  int lane = threadIdx.x & 63;
  const float* xp = x + ((size_t)gw << 9) + lane * 8;
  float4 u0 = *(const float4*)xp;
  float4 u1 = *(const float4*)(xp + 4);
  float v[8] = {u0.x,u0.y,u0.z,u0.w,u1.x,u1.y,u1.z,u1.w};
  float s = 0.f;
  #pragma unroll
  for (int j = 0; j < 8; ++j) s += v[j];
  #pragma unroll
  for (int off = 32; off; off >>= 1) s += __shfl_xor(s, off, 64);
  float mu = s * (1.f/512.f);
  float q = 0.f;
  #pragma unroll
  for (int j = 0; j < 8; ++j) { float d = v[j] - mu; q += d*d; }
  #pragma unroll
  for (int off = 32; off; off >>= 1) q += __shfl_xor(q, off, 64);
  float rstd = rsqrtf(q * (1.f/512.f) + 1e-5f);
  int dch = lane * 8;
  float4 w0 = *(const float4*)(w + dch),  w1 = *(const float4*)(w + dch + 4);
  float4 b0 = *(const float4*)(bv + dch), b1 = *(const float4*)(bv + dch + 4);
  float wv[8] = {w0.x,w0.y,w0.z,w0.w,w1.x,w1.y,w1.z,w1.w};
  float bb[8] = {b0.x,b0.y,b0.z,b0.w,b1.x,b1.y,b1.z,b1.w};
  bf16x8 ov;
  #pragma unroll
  for (int j = 0; j < 8; ++j) ov[j] = (__bf16)((v[j] - mu) * rstd * wv[j] + bb[j]);
  *(bf16x8*)(out + ((size_t)gw << 9) + dch) = ov;
}

// ---------------- depthwise 3x3 conv + bias + SiLU; xin fp32 -> u bf16 ----------------
__global__ __launch_bounds__(256) void conv_k(const float* __restrict__ xin, const float* __restrict__ cw,
                                              const float* __restrict__ cb, __bf16* __restrict__ u)
{
  int id = blockIdx.x * 256 + threadIdx.x;
  int dq = id & 127;
  int pos = id >> 7;
  int ww = pos & 31, hh = (pos >> 5) & 31, b = pos >> 10;
  int d = dq << 2;
  float4 acc = *(const float4*)(cb + d);
  #pragma unroll
  for (int kh = 0; kh < 3; ++kh) {
    int yy = hh + kh - 1;
    if (yy < 0 || yy > 31) continue;
    #pragma unroll
    for (int kw = 0; kw < 3; ++kw) {
      int xx = ww + kw - 1;
      if (xx < 0 || xx > 31) continue;
      float4 xv = *(const float4*)(xin + ((size_t)((b << 10) + (yy << 5) + xx) << 9) + d);
      float4 wv = *(const float4*)(cw + (size_t)((kh*3 + kw) << 9) + d);
      acc.x = fmaf(xv.x, wv.x, acc.x);
      acc.y = fmaf(xv.y, wv.y, acc.y);
      acc.z = fmaf(xv.z, wv.z, acc.z);
      acc.w = fmaf(xv.w, wv.w, acc.w);
    }
  }
  bf16x4 o;
  o[0] = (__bf16)(acc.x / (1.f + expf(-acc.x)));
  o[1] = (__bf16)(acc.y / (1.f + expf(-acc.y)));
  o[2] = (__bf16)(acc.z / (1.f + expf(-acc.z)));
  o[3] = (__bf16)(acc.w / (1.f + expf(-acc.w)));
  *(bf16x4*)(u + ((size_t)pos << 9) + d) = o;
}

// ================= Fully-fused 2D scan — 512 threads, 2 chunks/thread =================
// R6-R8 lesson: 1024-thread blocks are pinned at 64 VGPRs and the compiler's unroll
// load-batching (~32 live temps) spills regardless of source structure. At 512 threads
// (__launch_bounds__(512,2)) the cap is ~256 — batching fits, structurally spill-free.
// Each thread owns channel ch and chunks {c0, c0+16}. All partials park in bf16 LDS Y:
//   C-col fwd: Y = r*ap ; C-col bwd: Y = sc*(Y + r*ap)  [same-thread RMW]
//   barrier ; C-row fwd: Y += sc*(r*ap) ; C-row bwd: out = (Y + sc*r*ap + dd*u)*gate
// Per-chunk expf bases (not multiplicative chunk-offsets: a^512 * a^-512 = 0*inf = NaN
// at small a). T 64 KB + Y 64 KB + S 16 KB = 144 KB, 1 wg/CU, 8 waves.
__device__ __forceinline__ float sig_a(float al) {
  float a = 1.f / (1.f + expf(-al));
  return fminf(fmaxf(a, 1e-4f), 1.f - 1e-4f);
}

__global__ __launch_bounds__(512, 2) void scan2d_k(
    const __bf16* __restrict__ u, const float* __restrict__ alog,
    const float* __restrict__ bvec, const float* __restrict__ cvec, const float* __restrict__ dvec,
    const __bf16* __restrict__ gate, __bf16* __restrict__ yo)
{
  __shared__ __bf16 T[32768];       // u-tile [pos][32 ch]. 64 KB
  __shared__ __bf16 Y[32768];       // partial/result park [pos][32 ch]. 64 KB
  __shared__ float  S[4][32][32];   // chunk sums: rowF,rowB,colF,colB. 16 KB
  const int tid = threadIdx.x;
  const int cg  = blockIdx.x;       // channel group of 32
  const int b   = blockIdx.y;
  const int ch  = tid & 31;
  const int c0  = tid >> 5;         // 0..15; thread owns chunks c0 and c0+16
  const int d   = (cg << 5) + ch;

  const float a   = sig_a(alog[d]);
  const float lna = logf(a);
  const float ia  = 1.f / a;
  const float bb  = bvec[d];
  const float sc  = 0.25f * cvec[d];
  const float dd  = dvec[d];

  const __bf16* ub = u + ((size_t)b << 19) + (cg << 5);

  // ---- load tile: 8 x bf16x8 per thread, 16 B/lane coalesced ----
  #pragma unroll
  for (int i = 0; i < 8; ++i) {
    int flat = (tid + i * 512) << 3;
    int pos = flat >> 5;
    int c8  = flat & 31;
    *(bf16x8*)(T + flat) = *(const bf16x8*)(ub + (size_t)pos * 512 + c8);
  }
  __syncthreads();

  // one scan step: r += u*bb/max(apr,1e-20) with tracked reciprocal
  #define STEP(r_, uu_, apr_, rp_)                                 \
    { float rr_ = (apr_ < 1e-20f) ? 1e20f : rp_;                   \
      r_ = fmaf((uu_) * bb, rr_, r_); }
  // per-chunk scan bases (direct expf: safe at extreme a where offsets hit 0*inf)
  #define BASES(cc_)                                               \
    const float A0  = expf((float)((cc_) << 5) * lna);             \
    const float R0  = expf((float)((cc_) << 5) * -lna);            \
    const float A0B = expf((float)((31 - (cc_)) << 5) * lna);      \
    const float R0B = expf((float)((31 - (cc_)) << 5) * -lna);

  // ---- phase A: chunk partial sums (scalars only) ----
  #pragma unroll
  for (int k = 0; k < 2; ++k) {
    const int cc = c0 + (k << 4);
    BASES(cc)
    {
      float apr = A0, rp = R0, s = 0.f;
      #pragma unroll
      for (int j = 0; j < 32; ++j) {
        float uu = (float)T[((cc << 5) + j) * 32 + ch];
        STEP(s, uu, apr, rp) apr *= a; rp *= ia;
      }
      S[0][cc][ch] = s;
    }
    {
      float apr = A0B, rp = R0B, s = 0.f;
      #pragma unroll
      for (int j = 31; j >= 0; --j) {
        float uu = (float)T[((cc << 5) + j) * 32 + ch];
        STEP(s, uu, apr, rp) apr *= a; rp *= ia;
      }
      S[1][cc][ch] = s;
    }
    {
      float apr = A0, rp = R0, s = 0.f;
      #pragma unroll
      for (int j = 0; j < 32; ++j) {
        float uu = (float)T[((j << 5) | cc) * 32 + ch];
        STEP(s, uu, apr, rp) apr *= a; rp *= ia;
      }
      S[2][cc][ch] = s;
    }
    {
      float apr = A0B, rp = R0B, s = 0.f;
      #pragma unroll
      for (int j = 31; j >= 0; --j) {
        float uu = (float)T[((j << 5) | cc) * 32 + ch];
        STEP(s, uu, apr, rp) apr *= a; rp *= ia;
      }
      S[3][cc][ch] = s;
    }
  }
  __syncthreads();

  // ---- phase B: exclusive prefix (F arrays) / exclusive suffix (B arrays) ----
  if (tid < 128) {
    int arr = tid >> 5, ch2 = tid & 31;
    float run = 0.f;
    if ((arr & 1) == 0) {
      #pragma unroll
      for (int cc = 0; cc < 32; ++cc) { float v = S[arr][cc][ch2]; S[arr][cc][ch2] = run; run += v; }
    } else {
      #pragma unroll
      for (int cc = 31; cc >= 0; --cc) { float v = S[arr][cc][ch2]; S[arr][cc][ch2] = run; run += v; }
    }
  }
  __syncthreads();

  // ---- C-col: fwd raw partial -> Y; bwd finalize col in Y (same-thread RMW) ----
  #pragma unroll
  for (int k = 0; k < 2; ++k) {
    const int cc = c0 + (k << 4);
    BASES(cc)
    {
      float r = S[2][cc][ch], apr = A0, rp = R0;
      #pragma unroll
      for (int j = 0; j < 32; ++j) {
        int idx = ((j << 5) | cc) * 32 + ch;
        float uu = (float)T[idx];
        float ap = fmaxf(apr, 1e-20f);
        STEP(r, uu, apr, rp)
        Y[idx] = (__bf16)(r * ap);
        apr *= a; rp *= ia;
      }
    }
    {
      float r = S[3][cc][ch], apr = A0B, rp = R0B;
      #pragma unroll
      for (int j = 31; j >= 0; --j) {
        int idx = ((j << 5) | cc) * 32 + ch;
        float uu = (float)T[idx];
        float ap = fmaxf(apr, 1e-20f);
        STEP(r, uu, apr, rp)
        Y[idx] = (__bf16)(sc * ((float)Y[idx] + r * ap));
        apr *= a; rp *= ia;
      }
    }
  }
  __syncthreads();   // row threads read other threads' col finals

  // ---- C-row: fwd Y += sc*(r*ap); bwd finalize + d*u, *gate, write out ----
  const __bf16* gb = gate + ((size_t)b << 19) + (cg << 5) + ch;
  __bf16* yb = yo + ((size_t)b << 19) + (cg << 5) + ch;
  #pragma unroll
  for (int k = 0; k < 2; ++k) {
    const int cc = c0 + (k << 4);
    BASES(cc)
    {
      float r = S[0][cc][ch], apr = A0, rp = R0;
      #pragma unroll
      for (int j = 0; j < 32; ++j) {
        int idx = ((cc << 5) + j) * 32 + ch;
        float uu = (float)T[idx];
        float ap = fmaxf(apr, 1e-20f);
        STEP(r, uu, apr, rp)
        Y[idx] = (__bf16)((float)Y[idx] + sc * (r * ap));
        apr *= a; rp *= ia;
      }
    }
    {
      float r = S[1][cc][ch], apr = A0B, rp = R0B;
      #pragma unroll
      for (int j = 31; j >= 0; --j) {
        int p = (cc << 5) + j;
        int idx = p * 32 + ch;
        float uu = (float)T[idx];
        float ap = fmaxf(apr, 1e-20f);
        STEP(r, uu, apr, rp)
        float y = (float)Y[idx] + sc * (r * ap) + dd * uu;
        float g = (float)gb[(size_t)p * 512];
        yb[(size_t)p * 512] = (__bf16)(y * g);
        apr *= a; rp *= ia;
      }
    }
  }
  #undef STEP
  #undef BASES
}

// ---------------- mean over 1024 positions (bf16 in) -> (16, 512) fp32 ----------------
__global__ __launch_bounds__(64) void reduce_k(const __bf16* __restrict__ hn, float* __restrict__ out)
{
  int d = blockIdx.y * 64 + threadIdx.x;
  int b = blockIdx.x;
  const __bf16* p = hn + ((size_t)b << 19) + d;
  float s0 = 0.f, s1 = 0.f, s2 = 0.f, s3 = 0.f;
  for (int t = 0; t < 1024; t += 4) {
    s0 += (float)p[(size_t)(t+0) << 9];
    s1 += (float)p[(size_t)(t+1) << 9];
    s2 += (float)p[(size_t)(t+2) << 9];
    s3 += (float)p[(size_t)(t+3) << 9];
  }
  out[b * 512 + d] = (s0 + s1 + s2 + s3) * (1.f / 1024.f);
}

extern "C" void kernel_launch(void* const* d_in, const int* in_sizes, int n_in,
                              void* d_out, int out_size, void* d_ws, size_t ws_size,
                              hipStream_t stream)
{
  const float* tokens = (const float*)d_in[0];
  const float* in_w   = (const float*)d_in[1];
  const float* in_b   = (const float*)d_in[2];
  const float* nw     = (const float*)d_in[3];
  const float* nb     = (const float*)d_in[4];
  const float* iw     = (const float*)d_in[5];
  const float* ib     = (const float*)d_in[6];
  const float* cw     = (const float*)d_in[7];
  const float* cb     = (const float*)d_in[8];
  const float* al     = (const float*)d_in[9];
  const float* bbv    = (const float*)d_in[10];
  const float* ccv    = (const float*)d_in[11];
  const float* ddv    = (const float*)d_in[12];
  const float* ow     = (const float*)d_in[13];
  const float* obv    = (const float*)d_in[14];
  const float* onw    = (const float*)d_in[15];
  const float* onb    = (const float*)d_in[16];

  // workspace layout (148.9 MB):
  float*  x    = (float*)d_ws;                       // fp32 residual (33.5 MB)
  __bf16* hy16 = (__bf16*)(x + PP);                  // bf16 h / yg / final-ln (16.8 MB)
  float*  xin  = (float*)(hy16 + PP);                // fp32 x_in (33.5 MB)
  __bf16* g16  = (__bf16*)(xin + PP);                // bf16 gate (16.8 MB)
  __bf16* u16  = g16 + PP;                           // bf16 conv out (16.8 MB)
  __bf16* iwT  = u16 + PP;                           // 4x(1024x512) bf16 (4.2 MB)
  __bf16* owT  = iwT + (size_t)4 * 1024 * 512;       // 4x(512x512) bf16 (2.1 MB)
  __bf16* tb16 = owT + (size_t)4 * 512 * 512;        // tokens bf16 (25.2 MB)
  __bf16* inwT = (__bf16*)xin;                       // in_proj_w^T bf16 (pre-loop alias)

  // --- weight/input conversion (once per launch) ---
  cvt_k<<<6144, 256, 0, stream>>>(tokens, tb16);
  tr_k<<<dim3(16, 24, 1), 256, 0, stream>>>(in_w, inwT, 768, 512, 0, 0);
  tr_k<<<dim3(32, 16, 4), 256, 0, stream>>>(iw, iwT, 512, 1024, (size_t)512*1024, (size_t)1024*512);
  tr_k<<<dim3(16, 16, 4), 256, 0, stream>>>(ow, owT, 512, 512, (size_t)512*512, (size_t)512*512);

  // x = tokens @ in_proj_w + b
  gemm_bf_k<<<dim3(4, 128), 256, 0, stream>>>(tb16, inwT, in_b, nullptr, x, nullptr, 512, 768, 0);

  for (int i = 0; i < 4; ++i) {
    ln_k<<<4096, 256, 0, stream>>>(x, nw + i*512, nb + i*512, hy16);
    gemm_bf_k<<<dim3(8, 128), 256, 0, stream>>>(hy16, iwT + (size_t)i*1024*512, ib + i*1024,
                                                nullptr, xin, g16, 1024, 512, 1);
    conv_k<<<8192, 256, 0, stream>>>(xin, cw + i*9*512, cb + i*512, u16);
    scan2d_k<<<dim3(16, 16), 512, 0, stream>>>(u16, al + i*512, bbv + i*512, ccv + i*512,
                                               ddv + i*512, g16, hy16);
    gemm_bf_k<<<dim3(4, 128), 256, 0, stream>>>(hy16, owT + (size_t)i*512*512, obv + i*512,
                                                x, x, nullptr, 512, 512, 2);
  }

  ln_k<<<4096, 256, 0, stream>>>(x, onw, onb, hy16);
  reduce_k<<<dim3(16, 8), 64, 0, stream>>>(hy16, (float*)d_out);
}

// Round 10
// 750.805 us; speedup vs baseline: 1.2638x; 1.2638x over previous
//
#include <hip/hip_runtime.h>
#include <hip/hip_bf16.h>
#include <math.h>

#define NPOS 16384   // B*H*W = 16*32*32
#define DD   512
#define PP   ((size_t)NPOS * DD)   // 8388608 elements per plane

typedef __bf16 bf16x8 __attribute__((ext_vector_type(8)));
typedef __bf16 bf16x4 __attribute__((ext_vector_type(4)));
typedef float  f32x4  __attribute__((ext_vector_type(4)));

// async global->LDS, 16 B per lane; LDS dest = wave-uniform base + lane*16
__device__ __forceinline__ void g2lds16(const void* g, void* l) {
  __builtin_amdgcn_global_load_lds(
      (__attribute__((address_space(1))) void*)g,
      (__attribute__((address_space(3))) void*)l, 16, 0, 0);
}

// ================= bf16 MFMA GEMM, double-buffered LDS =================
// C = A(MxK) @ Bt^T + bias.  A: MxK bf16 (ld K). Bt: NxK bf16 (ld K).
// epi 0: C0 fp32 (ld N) = acc + bias
// epi 1: N=1024; cols<512 -> C0 fp32 (ld 512); cols>=512 -> sigmoid -> C1 bf16 (ld 512)
// epi 2: C0 fp32 (ld N) = acc + bias + res
__global__ __launch_bounds__(256, 3) void gemm_bf_k(
    const __bf16* __restrict__ A, const __bf16* __restrict__ Bt,
    const float* __restrict__ bias, const float* __restrict__ res,
    float* __restrict__ C0, __bf16* __restrict__ C1,
    int N, int K, int epi)
{
  __shared__ __bf16 Asm[2][128 * 32];
  __shared__ __bf16 Bsm[2][128 * 32];
  const int tid  = threadIdx.x;
  const int wave = tid >> 6;
  const int lane = tid & 63;
  const int quad = lane >> 4;
  const int l16  = lane & 15;
  const int bm = blockIdx.y * 128;
  const int bn = blockIdx.x * 128;
  const int wm = (wave >> 1) << 6;
  const int wn = (wave & 1) << 6;

  const int srow   = lane >> 2;                                  // row within 16-row stage
  const int schunk = (((lane & 3) ^ ((lane >> 3) & 3)) << 3);    // swizzled k-chunk (elements)

  f32x4 acc[4][4];
  const f32x4 z4 = {0.f, 0.f, 0.f, 0.f};
  #pragma unroll
  for (int i = 0; i < 4; ++i)
    #pragma unroll
    for (int j = 0; j < 4; ++j) acc[i][j] = z4;

  const __bf16* Ab = A  + (size_t)bm * K;
  const __bf16* Bb = Bt + (size_t)bn * K;
  const int nk = K >> 5;

  #define STAGE(buf, kb)                                                              \
    {                                                                                 \
      const int k0s = (kb) << 5;                                                      \
      _Pragma("unroll")                                                               \
      for (int c = 0; c < 2; ++c) {                                                   \
        const int cc = wave * 2 + c;                                                  \
        g2lds16(Ab + (size_t)(cc * 16 + srow) * K + k0s + schunk, &Asm[buf][cc * 512]);\
        g2lds16(Bb + (size_t)(cc * 16 + srow) * K + k0s + schunk, &Bsm[buf][cc * 512]);\
      }                                                                               \
    }

  STAGE(0, 0)
  int cur = 0;
  for (int kb = 0; kb < nk; ++kb) {
    __syncthreads();
    if (kb + 1 < nk) STAGE(cur ^ 1, kb + 1)
    bf16x8 af[4], bg[4];
    #pragma unroll
    for (int i = 0; i < 4; ++i) {
      int m = wm + i * 16 + l16;
      af[i] = *(const bf16x8*)(&Asm[cur][m * 32 + ((quad ^ ((m >> 1) & 3)) << 3)]);
    }
    #pragma unroll
    for (int j = 0; j < 4; ++j) {
      int n = wn + j * 16 + l16;
      bg[j] = *(const bf16x8*)(&Bsm[cur][n * 32 + ((quad ^ ((n >> 1) & 3)) << 3)]);
    }
    #pragma unroll
    for (int i = 0; i < 4; ++i)
      #pragma unroll
      for (int j = 0; j < 4; ++j)
        acc[i][j] = __builtin_amdgcn_mfma_f32_16x16x32_bf16(af[i], bg[j], acc[i][j], 0, 0, 0);
    cur ^= 1;
  }
  #undef STAGE

  // epilogue. C/D layout: col = lane&15, row = quad*4 + reg  [m89-verified]
  const bool dosig = (epi == 1) && (bn >= 512);
  #pragma unroll
  for (int j = 0; j < 4; ++j) {
    const int col = wn + j * 16 + l16;
    const float bv = bias[bn + col];
    #pragma unroll
    for (int i = 0; i < 4; ++i) {
      const int row0 = bm + wm + i * 16 + quad * 4;
      #pragma unroll
      for (int r = 0; r < 4; ++r) {
        float v = acc[i][j][r] + bv;
        if (epi == 1) {
          if (dosig) {
            v = 1.f / (1.f + expf(-v));
            C1[(size_t)(row0 + r) * 512 + (bn - 512) + col] = (__bf16)v;
          } else {
            C0[(size_t)(row0 + r) * 512 + bn + col] = v;
          }
        } else {
          size_t off = (size_t)(row0 + r) * N + bn + col;
          if (epi == 2) v += res[off];
          C0[off] = v;
        }
      }
    }
  }
}

// ---------------- fp32 -> bf16 elementwise (tokens) ----------------
__global__ __launch_bounds__(256) void cvt_k(const float* __restrict__ s, __bf16* __restrict__ d)
{
  size_t i = ((size_t)blockIdx.x * 256 + threadIdx.x) * 8;
  float4 a = *(const float4*)(s + i);
  float4 b = *(const float4*)(s + i + 4);
  bf16x8 v;
  v[0] = (__bf16)a.x; v[1] = (__bf16)a.y; v[2] = (__bf16)a.z; v[3] = (__bf16)a.w;
  v[4] = (__bf16)b.x; v[5] = (__bf16)b.y; v[6] = (__bf16)b.z; v[7] = (__bf16)b.w;
  *(bf16x8*)(d + i) = v;
}

// ---------------- transpose KxN fp32 -> NxK bf16 (weights) ----------------
__global__ __launch_bounds__(256) void tr_k(const float* __restrict__ src, __bf16* __restrict__ dst,
                                            int K, int N, size_t sstr, size_t dstr)
{
  __shared__ float t[32][33];
  const float* s = src + blockIdx.z * sstr;
  __bf16* d = dst + blockIdx.z * dstr;
  int n0 = blockIdx.x * 32, k0 = blockIdx.y * 32;
  int tx = threadIdx.x & 31, ty = threadIdx.x >> 5;   // 32x8
  #pragma unroll
  for (int i = 0; i < 4; ++i)
    t[ty + i * 8][tx] = s[(size_t)(k0 + ty + i * 8) * N + n0 + tx];
  __syncthreads();
  #pragma unroll
  for (int i = 0; i < 4; ++i)
    d[(size_t)(n0 + ty + i * 8) * K + k0 + tx] = (__bf16)t[tx][ty + i * 8];
}

// ---------------- LayerNorm over D=512, one wave per position, bf16 out ----------------
__global__ __launch_bounds__(256) void ln_k(const float* __restrict__ x, const float* __restrict__ w,
                                            const float* __restrict__ bv, __bf16* __restrict__ out)
{
  int gw = (blockIdx.x * 256 + threadIdx.x) >> 6;   // position
  int lane = threadIdx.x & 63;
  const float* xp = x + ((size_t)gw << 9) + lane * 8;
  float4 u0 = *(const float4*)xp;
  float4 u1 = *(const float4*)(xp + 4);
  float v[8] = {u0.x,u0.y,u0.z,u0.w,u1.x,u1.y,u1.z,u1.w};
  float s = 0.f;
  #pragma unroll
  for (int j = 0; j < 8; ++j) s += v[j];
  #pragma unroll
  for (int off = 32; off; off >>= 1) s += __shfl_xor(s, off, 64);
  float mu = s * (1.f/512.f);
  float q = 0.f;
  #pragma unroll
  for (int j = 0; j < 8; ++j) { float d = v[j] - mu; q += d*d; }
  #pragma unroll
  for (int off = 32; off; off >>= 1) q += __shfl_xor(q, off, 64);
  float rstd = rsqrtf(q * (1.f/512.f) + 1e-5f);
  int dch = lane * 8;
  float4 w0 = *(const float4*)(w + dch),  w1 = *(const float4*)(w + dch + 4);
  float4 b0 = *(const float4*)(bv + dch), b1 = *(const float4*)(bv + dch + 4);
  float wv[8] = {w0.x,w0.y,w0.z,w0.w,w1.x,w1.y,w1.z,w1.w};
  float bb[8] = {b0.x,b0.y,b0.z,b0.w,b1.x,b1.y,b1.z,b1.w};
  bf16x8 ov;
  #pragma unroll
  for (int j = 0; j < 8; ++j) ov[j] = (__bf16)((v[j] - mu) * rstd * wv[j] + bb[j]);
  *(bf16x8*)(out + ((size_t)gw << 9) + dch) = ov;
}

// ---------------- depthwise 3x3 conv + bias + SiLU; xin fp32 -> u bf16 ----------------
__global__ __launch_bounds__(256) void conv_k(const float* __restrict__ xin, const float* __restrict__ cw,
                                              const float* __restrict__ cb, __bf16* __restrict__ u)
{
  int id = blockIdx.x * 256 + threadIdx.x;
  int dq = id & 127;
  int pos = id >> 7;
  int ww = pos & 31, hh = (pos >> 5) & 31, b = pos >> 10;
  int d = dq << 2;
  float4 acc = *(const float4*)(cb + d);
  #pragma unroll
  for (int kh = 0; kh < 3; ++kh) {
    int yy = hh + kh - 1;
    if (yy < 0 || yy > 31) continue;
    #pragma unroll
    for (int kw = 0; kw < 3; ++kw) {
      int xx = ww + kw - 1;
      if (xx < 0 || xx > 31) continue;
      float4 xv = *(const float4*)(xin + ((size_t)((b << 10) + (yy << 5) + xx) << 9) + d);
      float4 wv = *(const float4*)(cw + (size_t)((kh*3 + kw) << 9) + d);
      acc.x = fmaf(xv.x, wv.x, acc.x);
      acc.y = fmaf(xv.y, wv.y, acc.y);
      acc.z = fmaf(xv.z, wv.z, acc.z);
      acc.w = fmaf(xv.w, wv.w, acc.w);
    }
  }
  bf16x4 o;
  o[0] = (__bf16)(acc.x / (1.f + expf(-acc.x)));
  o[1] = (__bf16)(acc.y / (1.f + expf(-acc.y)));
  o[2] = (__bf16)(acc.z / (1.f + expf(-acc.z)));
  o[3] = (__bf16)(acc.w / (1.f + expf(-acc.w)));
  *(bf16x4*)(u + ((size_t)pos << 9) + d) = o;
}

// ================= Fully-fused 2D scan — bounded-unroll, spill-proof =================
// R9 lesson: the spill came from the scheduler batching ds_read_u16 across the four
// independent fully-unrolled phase-A sub-loops (~128 live temps). Fixes:
//  (1) phase A's 4 passes fused into ONE loop (fwd uses t=j, bwd uses t=31-j; row/col
//      share apr/rp chains) -> 4 independent FMA chains, ~14 live floats;
//  (2) #pragma unroll 4 on every 32-iter scan loop, unroll 1 on chunk loops -> batch
//      <= 16 loads. Peak live ~40 regs << 128 cap (512 threads, launch_bounds(512,2)).
// All partials park in bf16 LDS Y via same-thread RMW (R8 scheme). 144 KB LDS, 1 wg/CU.
__device__ __forceinline__ float sig_a(float al) {
  float a = 1.f / (1.f + expf(-al));
  return fminf(fmaxf(a, 1e-4f), 1.f - 1e-4f);
}

__global__ __launch_bounds__(512, 2) void scan2d_k(
    const __bf16* __restrict__ u, const float* __restrict__ alog,
    const float* __restrict__ bvec, const float* __restrict__ cvec, const float* __restrict__ dvec,
    const __bf16* __restrict__ gate, __bf16* __restrict__ yo)
{
  __shared__ __bf16 T[32768];       // u-tile [pos][32 ch]. 64 KB
  __shared__ __bf16 Y[32768];       // partial/result park [pos][32 ch]. 64 KB
  __shared__ float  S[4][32][32];   // chunk sums: rowF,rowB,colF,colB. 16 KB
  const int tid = threadIdx.x;
  const int cg  = blockIdx.x;       // channel group of 32
  const int b   = blockIdx.y;
  const int ch  = tid & 31;
  const int c0  = tid >> 5;         // 0..15; thread owns chunks c0 and c0+16
  const int d   = (cg << 5) + ch;

  const float a   = sig_a(alog[d]);
  const float lna = logf(a);
  const float ia  = 1.f / a;
  const float bb  = bvec[d];
  const float sc  = 0.25f * cvec[d];
  const float dd  = dvec[d];

  const __bf16* ub = u + ((size_t)b << 19) + (cg << 5);

  // ---- load tile: 8 x bf16x8 per thread, 16 B/lane coalesced ----
  #pragma unroll
  for (int i = 0; i < 8; ++i) {
    int flat = (tid + i * 512) << 3;
    int pos = flat >> 5;
    int c8  = flat & 31;
    *(bf16x8*)(T + flat) = *(const bf16x8*)(ub + (size_t)pos * 512 + c8);
  }
  __syncthreads();

  // one scan step: r += u*bb/max(apr,1e-20) with tracked reciprocal
  #define STEP(r_, uu_, apr_, rp_)                                 \
    { float rr_ = (apr_ < 1e-20f) ? 1e20f : rp_;                   \
      r_ = fmaf((uu_) * bb, rr_, r_); }
  // per-chunk scan bases (direct expf: safe at extreme a where offsets hit 0*inf)
  #define BASES(cc_)                                               \
    const float A0  = expf((float)((cc_) << 5) * lna);             \
    const float R0  = expf((float)((cc_) << 5) * -lna);            \
    const float A0B = expf((float)((31 - (cc_)) << 5) * lna);      \
    const float R0B = expf((float)((31 - (cc_)) << 5) * -lna);

  // ---- phase A: all 4 chunk sums in one loop per chunk ----
  #pragma unroll 1
  for (int k = 0; k < 2; ++k) {
    const int cc = c0 + (k << 4);
    BASES(cc)
    float apr = A0, rp = R0, aprB = A0B, rpB = R0B;
    float s0 = 0.f, s1 = 0.f, s2 = 0.f, s3 = 0.f;
    #pragma unroll 4
    for (int j = 0; j < 32; ++j) {
      // fwd passes consume t=j; bwd passes consume t=31-j (first bwd step = t31 @ A0B)
      float urf = (float)T[((cc << 5) + j) * 32 + ch];
      float urb = (float)T[((cc << 5) + (31 - j)) * 32 + ch];
      float ucf = (float)T[((j << 5) | cc) * 32 + ch];
      float ucb = (float)T[(((31 - j) << 5) | cc) * 32 + ch];
      STEP(s0, urf, apr, rp)
      STEP(s2, ucf, apr, rp)
      STEP(s1, urb, aprB, rpB)
      STEP(s3, ucb, aprB, rpB)
      apr *= a; rp *= ia; aprB *= a; rpB *= ia;
    }
    S[0][cc][ch] = s0; S[1][cc][ch] = s1;
    S[2][cc][ch] = s2; S[3][cc][ch] = s3;
  }
  __syncthreads();

  // ---- phase B: exclusive prefix (F arrays) / exclusive suffix (B arrays) ----
  if (tid < 128) {
    int arr = tid >> 5, ch2 = tid & 31;
    float run = 0.f;
    if ((arr & 1) == 0) {
      #pragma unroll 4
      for (int cc = 0; cc < 32; ++cc) { float v = S[arr][cc][ch2]; S[arr][cc][ch2] = run; run += v; }
    } else {
      #pragma unroll 4
      for (int cc = 31; cc >= 0; --cc) { float v = S[arr][cc][ch2]; S[arr][cc][ch2] = run; run += v; }
    }
  }
  __syncthreads();

  // ---- C-col: fwd raw partial -> Y; bwd finalize col in Y (same-thread RMW) ----
  #pragma unroll 1
  for (int k = 0; k < 2; ++k) {
    const int cc = c0 + (k << 4);
    BASES(cc)
    {
      float r = S[2][cc][ch], apr = A0, rp = R0;
      #pragma unroll 4
      for (int j = 0; j < 32; ++j) {
        int idx = ((j << 5) | cc) * 32 + ch;
        float uu = (float)T[idx];
        float ap = fmaxf(apr, 1e-20f);
        STEP(r, uu, apr, rp)
        Y[idx] = (__bf16)(r * ap);
        apr *= a; rp *= ia;
      }
    }
    {
      float r = S[3][cc][ch], apr = A0B, rp = R0B;
      #pragma unroll 4
      for (int j = 31; j >= 0; --j) {
        int idx = ((j << 5) | cc) * 32 + ch;
        float uu = (float)T[idx];
        float ap = fmaxf(apr, 1e-20f);
        STEP(r, uu, apr, rp)
        Y[idx] = (__bf16)(sc * ((float)Y[idx] + r * ap));
        apr *= a; rp *= ia;
      }
    }
  }
  __syncthreads();   // row threads read other threads' col finals

  // ---- C-row: fwd Y += sc*(r*ap); bwd finalize + d*u, *gate, write out ----
  const __bf16* gb = gate + ((size_t)b << 19) + (cg << 5) + ch;
  __bf16* yb = yo + ((size_t)b << 19) + (cg << 5) + ch;
  #pragma unroll 1
  for (int k = 0; k < 2; ++k) {
    const int cc = c0 + (k << 4);
    BASES(cc)
    {
      float r = S[0][cc][ch], apr = A0, rp = R0;
      #pragma unroll 4
      for (int j = 0; j < 32; ++j) {
        int idx = ((cc << 5) + j) * 32 + ch;
        float uu = (float)T[idx];
        float ap = fmaxf(apr, 1e-20f);
        STEP(r, uu, apr, rp)
        Y[idx] = (__bf16)((float)Y[idx] + sc * (r * ap));
        apr *= a; rp *= ia;
      }
    }
    {
      float r = S[1][cc][ch], apr = A0B, rp = R0B;
      #pragma unroll 4
      for (int j = 31; j >= 0; --j) {
        int p = (cc << 5) + j;
        int idx = p * 32 + ch;
        float uu = (float)T[idx];
        float ap = fmaxf(apr, 1e-20f);
        STEP(r, uu, apr, rp)
        float y = (float)Y[idx] + sc * (r * ap) + dd * uu;
        float g = (float)gb[(size_t)p * 512];
        yb[(size_t)p * 512] = (__bf16)(y * g);
        apr *= a; rp *= ia;
      }
    }
  }
  #undef STEP
  #undef BASES
}

// ---------------- mean over 1024 positions (bf16 in) -> (16, 512) fp32 ----------------
__global__ __launch_bounds__(64) void reduce_k(const __bf16* __restrict__ hn, float* __restrict__ out)
{
  int d = blockIdx.y * 64 + threadIdx.x;
  int b = blockIdx.x;
  const __bf16* p = hn + ((size_t)b << 19) + d;
  float s0 = 0.f, s1 = 0.f, s2 = 0.f, s3 = 0.f;
  for (int t = 0; t < 1024; t += 4) {
    s0 += (float)p[(size_t)(t+0) << 9];
    s1 += (float)p[(size_t)(t+1) << 9];
    s2 += (float)p[(size_t)(t+2) << 9];
    s3 += (float)p[(size_t)(t+3) << 9];
  }
  out[b * 512 + d] = (s0 + s1 + s2 + s3) * (1.f / 1024.f);
}

extern "C" void kernel_launch(void* const* d_in, const int* in_sizes, int n_in,
                              void* d_out, int out_size, void* d_ws, size_t ws_size,
                              hipStream_t stream)
{
  const float* tokens = (const float*)d_in[0];
  const float* in_w   = (const float*)d_in[1];
  const float* in_b   = (const float*)d_in[2];
  const float* nw     = (const float*)d_in[3];
  const float* nb     = (const float*)d_in[4];
  const float* iw     = (const float*)d_in[5];
  const float* ib     = (const float*)d_in[6];
  const float* cw     = (const float*)d_in[7];
  const float* cb     = (const float*)d_in[8];
  const float* al     = (const float*)d_in[9];
  const float* bbv    = (const float*)d_in[10];
  const float* ccv    = (const float*)d_in[11];
  const float* ddv    = (const float*)d_in[12];
  const float* ow     = (const float*)d_in[13];
  const float* obv    = (const float*)d_in[14];
  const float* onw    = (const float*)d_in[15];
  const float* onb    = (const float*)d_in[16];

  // workspace layout (148.9 MB):
  float*  x    = (float*)d_ws;                       // fp32 residual (33.5 MB)
  __bf16* hy16 = (__bf16*)(x + PP);                  // bf16 h / yg / final-ln (16.8 MB)
  float*  xin  = (float*)(hy16 + PP);                // fp32 x_in (33.5 MB)
  __bf16* g16  = (__bf16*)(xin + PP);                // bf16 gate (16.8 MB)
  __bf16* u16  = g16 + PP;                           // bf16 conv out (16.8 MB)
  __bf16* iwT  = u16 + PP;                           // 4x(1024x512) bf16 (4.2 MB)
  __bf16* owT  = iwT + (size_t)4 * 1024 * 512;       // 4x(512x512) bf16 (2.1 MB)
  __bf16* tb16 = owT + (size_t)4 * 512 * 512;        // tokens bf16 (25.2 MB)
  __bf16* inwT = (__bf16*)xin;                       // in_proj_w^T bf16 (pre-loop alias)

  // --- weight/input conversion (once per launch) ---
  cvt_k<<<6144, 256, 0, stream>>>(tokens, tb16);
  tr_k<<<dim3(16, 24, 1), 256, 0, stream>>>(in_w, inwT, 768, 512, 0, 0);
  tr_k<<<dim3(32, 16, 4), 256, 0, stream>>>(iw, iwT, 512, 1024, (size_t)512*1024, (size_t)1024*512);
  tr_k<<<dim3(16, 16, 4), 256, 0, stream>>>(ow, owT, 512, 512, (size_t)512*512, (size_t)512*512);

  // x = tokens @ in_proj_w + b
  gemm_bf_k<<<dim3(4, 128), 256, 0, stream>>>(tb16, inwT, in_b, nullptr, x, nullptr, 512, 768, 0);

  for (int i = 0; i < 4; ++i) {
    ln_k<<<4096, 256, 0, stream>>>(x, nw + i*512, nb + i*512, hy16);
    gemm_bf_k<<<dim3(8, 128), 256, 0, stream>>>(hy16, iwT + (size_t)i*1024*512, ib + i*1024,
                                                nullptr, xin, g16, 1024, 512, 1);
    conv_k<<<8192, 256, 0, stream>>>(xin, cw + i*9*512, cb + i*512, u16);
    scan2d_k<<<dim3(16, 16), 512, 0, stream>>>(u16, al + i*512, bbv + i*512, ccv + i*512,
                                               ddv + i*512, g16, hy16);
    gemm_bf_k<<<dim3(4, 128), 256, 0, stream>>>(hy16, owT + (size_t)i*512*512, obv + i*512,
                                                x, x, nullptr, 512, 512, 2);
  }

  ln_k<<<4096, 256, 0, stream>>>(x, onw, onb, hy16);
  reduce_k<<<dim3(16, 8), 64, 0, stream>>>(hy16, (float*)d_out);
}

// Round 11
// 670.232 us; speedup vs baseline: 1.4157x; 1.1202x over previous
//
#include <hip/hip_runtime.h>
#include <hip/hip_bf16.h>
#include <math.h>

#define NPOS 16384   // B*H*W = 16*32*32
#define DD   512
#define PP   ((size_t)NPOS * DD)   // 8388608 elements per plane

typedef __bf16 bf16x8 __attribute__((ext_vector_type(8)));
typedef __bf16 bf16x4 __attribute__((ext_vector_type(4)));
typedef float  f32x4  __attribute__((ext_vector_type(4)));

// async global->LDS, 16 B per lane; LDS dest = wave-uniform base + lane*16
__device__ __forceinline__ void g2lds16(const void* g, void* l) {
  __builtin_amdgcn_global_load_lds(
      (__attribute__((address_space(1))) void*)g,
      (__attribute__((address_space(3))) void*)l, 16, 0, 0);
}

// ================= bf16 MFMA GEMM, double-buffered LDS =================
// C = A(MxK) @ Bt^T + bias.  A: MxK bf16 (ld K). Bt: NxK bf16 (ld K).
// Grid: blockIdx.x = M-tile (fastest), blockIdx.y = N-tile. XCD-aware: the
// bn-blocks sharing one A-tile have ids == bm (mod 8) -> same XCD -> A-tile
// stays in that XCD's 4MB L2 (R10: 8 XCDs each fetched A separately, 66 MB).
// epi 0: C0 fp32 (ld N) = acc + bias
// epi 1: N=1024; cols<512 -> C1b bf16 (ld 512); cols>=512 -> sigmoid -> C1 bf16 (ld 512)
// epi 2: C0 fp32 (ld N) = acc + bias + res
__global__ __launch_bounds__(256, 3) void gemm_bf_k(
    const __bf16* __restrict__ A, const __bf16* __restrict__ Bt,
    const float* __restrict__ bias, const float* __restrict__ res,
    float* __restrict__ C0, __bf16* __restrict__ C1, __bf16* __restrict__ C1b,
    int N, int K, int epi)
{
  __shared__ __bf16 Asm[2][128 * 32];
  __shared__ __bf16 Bsm[2][128 * 32];
  const int tid  = threadIdx.x;
  const int wave = tid >> 6;
  const int lane = tid & 63;
  const int quad = lane >> 4;
  const int l16  = lane & 15;
  const int bm = blockIdx.x * 128;   // M fastest -> A-sharers on same XCD
  const int bn = blockIdx.y * 128;
  const int wm = (wave >> 1) << 6;
  const int wn = (wave & 1) << 6;

  const int srow   = lane >> 2;                                  // row within 16-row stage
  const int schunk = (((lane & 3) ^ ((lane >> 3) & 3)) << 3);    // swizzled k-chunk (elements)

  f32x4 acc[4][4];
  const f32x4 z4 = {0.f, 0.f, 0.f, 0.f};
  #pragma unroll
  for (int i = 0; i < 4; ++i)
    #pragma unroll
    for (int j = 0; j < 4; ++j) acc[i][j] = z4;

  const __bf16* Ab = A  + (size_t)bm * K;
  const __bf16* Bb = Bt + (size_t)bn * K;
  const int nk = K >> 5;

  #define STAGE(buf, kb)                                                              \
    {                                                                                 \
      const int k0s = (kb) << 5;                                                      \
      _Pragma("unroll")                                                               \
      for (int c = 0; c < 2; ++c) {                                                   \
        const int cc = wave * 2 + c;                                                  \
        g2lds16(Ab + (size_t)(cc * 16 + srow) * K + k0s + schunk, &Asm[buf][cc * 512]);\
        g2lds16(Bb + (size_t)(cc * 16 + srow) * K + k0s + schunk, &Bsm[buf][cc * 512]);\
      }                                                                               \
    }

  STAGE(0, 0)
  int cur = 0;
  for (int kb = 0; kb < nk; ++kb) {
    __syncthreads();
    if (kb + 1 < nk) STAGE(cur ^ 1, kb + 1)
    bf16x8 af[4], bg[4];
    #pragma unroll
    for (int i = 0; i < 4; ++i) {
      int m = wm + i * 16 + l16;
      af[i] = *(const bf16x8*)(&Asm[cur][m * 32 + ((quad ^ ((m >> 1) & 3)) << 3)]);
    }
    #pragma unroll
    for (int j = 0; j < 4; ++j) {
      int n = wn + j * 16 + l16;
      bg[j] = *(const bf16x8*)(&Bsm[cur][n * 32 + ((quad ^ ((n >> 1) & 3)) << 3)]);
    }
    #pragma unroll
    for (int i = 0; i < 4; ++i)
      #pragma unroll
      for (int j = 0; j < 4; ++j)
        acc[i][j] = __builtin_amdgcn_mfma_f32_16x16x32_bf16(af[i], bg[j], acc[i][j], 0, 0, 0);
    cur ^= 1;
  }
  #undef STAGE

  // epilogue. C/D layout: col = lane&15, row = quad*4 + reg  [m89-verified]
  const bool dosig = (epi == 1) && (bn >= 512);
  #pragma unroll
  for (int j = 0; j < 4; ++j) {
    const int col = wn + j * 16 + l16;
    const float bv = bias[bn + col];
    #pragma unroll
    for (int i = 0; i < 4; ++i) {
      const int row0 = bm + wm + i * 16 + quad * 4;
      #pragma unroll
      for (int r = 0; r < 4; ++r) {
        float v = acc[i][j][r] + bv;
        if (epi == 1) {
          if (dosig) {
            v = 1.f / (1.f + expf(-v));
            C1[(size_t)(row0 + r) * 512 + (bn - 512) + col] = (__bf16)v;
          } else {
            C1b[(size_t)(row0 + r) * 512 + bn + col] = (__bf16)v;
          }
        } else {
          size_t off = (size_t)(row0 + r) * N + bn + col;
          if (epi == 2) v += res[off];
          C0[off] = v;
        }
      }
    }
  }
}

// ---------------- fp32 -> bf16 elementwise (tokens) ----------------
__global__ __launch_bounds__(256) void cvt_k(const float* __restrict__ s, __bf16* __restrict__ d)
{
  size_t i = ((size_t)blockIdx.x * 256 + threadIdx.x) * 8;
  float4 a = *(const float4*)(s + i);
  float4 b = *(const float4*)(s + i + 4);
  bf16x8 v;
  v[0] = (__bf16)a.x; v[1] = (__bf16)a.y; v[2] = (__bf16)a.z; v[3] = (__bf16)a.w;
  v[4] = (__bf16)b.x; v[5] = (__bf16)b.y; v[6] = (__bf16)b.z; v[7] = (__bf16)b.w;
  *(bf16x8*)(d + i) = v;
}

// ---------------- transpose KxN fp32 -> NxK bf16 (weights) ----------------
__global__ __launch_bounds__(256) void tr_k(const float* __restrict__ src, __bf16* __restrict__ dst,
                                            int K, int N, size_t sstr, size_t dstr)
{
  __shared__ float t[32][33];
  const float* s = src + blockIdx.z * sstr;
  __bf16* d = dst + blockIdx.z * dstr;
  int n0 = blockIdx.x * 32, k0 = blockIdx.y * 32;
  int tx = threadIdx.x & 31, ty = threadIdx.x >> 5;   // 32x8
  #pragma unroll
  for (int i = 0; i < 4; ++i)
    t[ty + i * 8][tx] = s[(size_t)(k0 + ty + i * 8) * N + n0 + tx];
  __syncthreads();
  #pragma unroll
  for (int i = 0; i < 4; ++i)
    d[(size_t)(n0 + ty + i * 8) * K + k0 + tx] = (__bf16)t[tx][ty + i * 8];
}

// ---------------- LayerNorm over D=512, one wave per position, bf16 out ----------------
__global__ __launch_bounds__(256) void ln_k(const float* __restrict__ x, const float* __restrict__ w,
                                            const float* __restrict__ bv, __bf16* __restrict__ out)
{
  int gw = (blockIdx.x * 256 + threadIdx.x) >> 6;   // position
  int lane = threadIdx.x & 63;
  const float* xp = x + ((size_t)gw << 9) + lane * 8;
  float4 u0 = *(const float4*)xp;
  float4 u1 = *(const float4*)(xp + 4);
  float v[8] = {u0.x,u0.y,u0.z,u0.w,u1.x,u1.y,u1.z,u1.w};
  float s = 0.f;
  #pragma unroll
  for (int j = 0; j < 8; ++j) s += v[j];
  #pragma unroll
  for (int off = 32; off; off >>= 1) s += __shfl_xor(s, off, 64);
  float mu = s * (1.f/512.f);
  float q = 0.f;
  #pragma unroll
  for (int j = 0; j < 8; ++j) { float d = v[j] - mu; q += d*d; }
  #pragma unroll
  for (int off = 32; off; off >>= 1) q += __shfl_xor(q, off, 64);
  float rstd = rsqrtf(q * (1.f/512.f) + 1e-5f);
  int dch = lane * 8;
  float4 w0 = *(const float4*)(w + dch),  w1 = *(const float4*)(w + dch + 4);
  float4 b0 = *(const float4*)(bv + dch), b1 = *(const float4*)(bv + dch + 4);
  float wv[8] = {w0.x,w0.y,w0.z,w0.w,w1.x,w1.y,w1.z,w1.w};
  float bb[8] = {b0.x,b0.y,b0.z,b0.w,b1.x,b1.y,b1.z,b1.w};
  bf16x8 ov;
  #pragma unroll
  for (int j = 0; j < 8; ++j) ov[j] = (__bf16)((v[j] - mu) * rstd * wv[j] + bb[j]);
  *(bf16x8*)(out + ((size_t)gw << 9) + dch) = ov;
}

// ================= Fully-fused conv + 2D scan =================
// One block = (batch b, 32-channel group); LDS: T (xin tile / partial park, 64 KB) +
// Y (u = silu(dwconv(xin)+bias), 64 KB) + S (16 KB) = 144 KB, 1 wg/CU.
// The block holds the full 32x32 spatial grid for its channels -> conv has NO halo.
// Phase 0: 3x3 depthwise conv, sliding 3x3 window over T rows (cc, cc+16) -> Y.
// Then R10's scan phases, reading u from Y, parking partials in T (xin dead post-conv):
//   A: 4 chunk sums fused in one loop; B: exclusive prefix/suffix in S;
//   C-col fwd: T=r*ap; C-col bwd: T=sc*(T+r*ap); barrier;
//   C-row fwd: T+=sc*r*ap; C-row bwd: out=(T+sc*r*ap+dd*u)*gate.
// Bounded unroll everywhere (R9/R10 lesson: scheduler load-batching is the spiller).
__device__ __forceinline__ float sig_a(float al) {
  float a = 1.f / (1.f + expf(-al));
  return fminf(fmaxf(a, 1e-4f), 1.f - 1e-4f);
}

__global__ __launch_bounds__(512, 2) void scan2d_k(
    const __bf16* __restrict__ xin, const float* __restrict__ cw, const float* __restrict__ cb,
    const float* __restrict__ alog, const float* __restrict__ bvec, const float* __restrict__ cvec,
    const float* __restrict__ dvec, const __bf16* __restrict__ gate, __bf16* __restrict__ yo)
{
  __shared__ __bf16 T[32768];       // xin tile [pos][32 ch]; partial park in phase C. 64 KB
  __shared__ __bf16 Y[32768];       // u tile. 64 KB
  __shared__ float  S[4][32][32];   // chunk sums: rowF,rowB,colF,colB. 16 KB
  const int tid = threadIdx.x;
  const int cg  = blockIdx.x;       // channel group of 32
  const int b   = blockIdx.y;
  const int ch  = tid & 31;
  const int c0  = tid >> 5;         // 0..15; thread owns chunks/rows c0 and c0+16
  const int d   = (cg << 5) + ch;

  const float a   = sig_a(alog[d]);
  const float lna = logf(a);
  const float ia  = 1.f / a;
  const float bb  = bvec[d];
  const float sc  = 0.25f * cvec[d];
  const float dd  = dvec[d];

  const __bf16* ub = xin + ((size_t)b << 19) + (cg << 5);

  // ---- load xin tile: 8 x bf16x8 per thread, 16 B/lane coalesced ----
  #pragma unroll
  for (int i = 0; i < 8; ++i) {
    int flat = (tid + i * 512) << 3;
    int pos = flat >> 5;
    int c8  = flat & 31;
    *(bf16x8*)(T + flat) = *(const bf16x8*)(ub + (size_t)pos * 512 + c8);
  }
  // conv weights while loads are in flight
  float w00 = cw[(0 << 9) + d], w01 = cw[(1 << 9) + d], w02 = cw[(2 << 9) + d];
  float w10 = cw[(3 << 9) + d], w11 = cw[(4 << 9) + d], w12 = cw[(5 << 9) + d];
  float w20 = cw[(6 << 9) + d], w21 = cw[(7 << 9) + d], w22 = cw[(8 << 9) + d];
  const float cbv = cb[d];
  __syncthreads();

  // ---- phase 0: depthwise 3x3 conv + SiLU, rows c0 and c0+16 -> Y ----
  #pragma unroll 1
  for (int k = 0; k < 2; ++k) {
    const int hh = c0 + (k << 4);
    const int ym = hh - 1, yp = hh + 1;
    const bool up = (ym >= 0), dn = (yp < 32);
    float a0 = 0.f, a1 = 0.f, a2 = 0.f;                       // col xx-1
    float b0 = up ? (float)T[((ym << 5) + 0) * 32 + ch] : 0.f; // col xx
    float b1 =      (float)T[((hh << 5) + 0) * 32 + ch];
    float b2 = dn ? (float)T[((yp << 5) + 0) * 32 + ch] : 0.f;
    #pragma unroll 4
    for (int ww = 0; ww < 32; ++ww) {
      float e0 = 0.f, e1 = 0.f, e2 = 0.f;                      // col xx+1
      if (ww < 31) {
        e0 = up ? (float)T[((ym << 5) + ww + 1) * 32 + ch] : 0.f;
        e1 =      (float)T[((hh << 5) + ww + 1) * 32 + ch];
        e2 = dn ? (float)T[((yp << 5) + ww + 1) * 32 + ch] : 0.f;
      }
      float acc = cbv;
      acc = fmaf(a0, w00, acc); acc = fmaf(b0, w01, acc); acc = fmaf(e0, w02, acc);
      acc = fmaf(a1, w10, acc); acc = fmaf(b1, w11, acc); acc = fmaf(e1, w12, acc);
      acc = fmaf(a2, w20, acc); acc = fmaf(b2, w21, acc); acc = fmaf(e2, w22, acc);
      acc = acc / (1.f + expf(-acc));
      Y[((hh << 5) + ww) * 32 + ch] = (__bf16)acc;
      a0 = b0; a1 = b1; a2 = b2; b0 = e0; b1 = e1; b2 = e2;
    }
  }
  __syncthreads();

  // one scan step: r += u*bb/max(apr,1e-20) with tracked reciprocal
  #define STEP(r_, uu_, apr_, rp_)                                 \
    { float rr_ = (apr_ < 1e-20f) ? 1e20f : rp_;                   \
      r_ = fmaf((uu_) * bb, rr_, r_); }
  // per-chunk scan bases (direct expf: safe at extreme a where offsets hit 0*inf)
  #define BASES(cc_)                                               \
    const float A0  = expf((float)((cc_) << 5) * lna);             \
    const float R0  = expf((float)((cc_) << 5) * -lna);            \
    const float A0B = expf((float)((31 - (cc_)) << 5) * lna);      \
    const float R0B = expf((float)((31 - (cc_)) << 5) * -lna);

  // ---- phase A: all 4 chunk sums in one loop per chunk ----
  #pragma unroll 1
  for (int k = 0; k < 2; ++k) {
    const int cc = c0 + (k << 4);
    BASES(cc)
    float apr = A0, rp = R0, aprB = A0B, rpB = R0B;
    float s0 = 0.f, s1 = 0.f, s2 = 0.f, s3 = 0.f;
    #pragma unroll 4
    for (int j = 0; j < 32; ++j) {
      float urf = (float)Y[((cc << 5) + j) * 32 + ch];
      float urb = (float)Y[((cc << 5) + (31 - j)) * 32 + ch];
      float ucf = (float)Y[((j << 5) | cc) * 32 + ch];
      float ucb = (float)Y[(((31 - j) << 5) | cc) * 32 + ch];
      STEP(s0, urf, apr, rp)
      STEP(s2, ucf, apr, rp)
      STEP(s1, urb, aprB, rpB)
      STEP(s3, ucb, aprB, rpB)
      apr *= a; rp *= ia; aprB *= a; rpB *= ia;
    }
    S[0][cc][ch] = s0; S[1][cc][ch] = s1;
    S[2][cc][ch] = s2; S[3][cc][ch] = s3;
  }
  __syncthreads();

  // ---- phase B: exclusive prefix (F arrays) / exclusive suffix (B arrays) ----
  if (tid < 128) {
    int arr = tid >> 5, ch2 = tid & 31;
    float run = 0.f;
    if ((arr & 1) == 0) {
      #pragma unroll 4
      for (int cc = 0; cc < 32; ++cc) { float v = S[arr][cc][ch2]; S[arr][cc][ch2] = run; run += v; }
    } else {
      #pragma unroll 4
      for (int cc = 31; cc >= 0; --cc) { float v = S[arr][cc][ch2]; S[arr][cc][ch2] = run; run += v; }
    }
  }
  __syncthreads();

  // ---- C-col: fwd raw partial -> T; bwd finalize col in T (same-thread RMW) ----
  #pragma unroll 1
  for (int k = 0; k < 2; ++k) {
    const int cc = c0 + (k << 4);
    BASES(cc)
    {
      float r = S[2][cc][ch], apr = A0, rp = R0;
      #pragma unroll 4
      for (int j = 0; j < 32; ++j) {
        int idx = ((j << 5) | cc) * 32 + ch;
        float uu = (float)Y[idx];
        float ap = fmaxf(apr, 1e-20f);
        STEP(r, uu, apr, rp)
        T[idx] = (__bf16)(r * ap);
        apr *= a; rp *= ia;
      }
    }
    {
      float r = S[3][cc][ch], apr = A0B, rp = R0B;
      #pragma unroll 4
      for (int j = 31; j >= 0; --j) {
        int idx = ((j << 5) | cc) * 32 + ch;
        float uu = (float)Y[idx];
        float ap = fmaxf(apr, 1e-20f);
        STEP(r, uu, apr, rp)
        T[idx] = (__bf16)(sc * ((float)T[idx] + r * ap));
        apr *= a; rp *= ia;
      }
    }
  }
  __syncthreads();   // row threads read other threads' col finals

  // ---- C-row: fwd T += sc*(r*ap); bwd finalize + d*u, *gate, write out ----
  const __bf16* gb = gate + ((size_t)b << 19) + (cg << 5) + ch;
  __bf16* yb = yo + ((size_t)b << 19) + (cg << 5) + ch;
  #pragma unroll 1
  for (int k = 0; k < 2; ++k) {
    const int cc = c0 + (k << 4);
    BASES(cc)
    {
      float r = S[0][cc][ch], apr = A0, rp = R0;
      #pragma unroll 4
      for (int j = 0; j < 32; ++j) {
        int idx = ((cc << 5) + j) * 32 + ch;
        float uu = (float)Y[idx];
        float ap = fmaxf(apr, 1e-20f);
        STEP(r, uu, apr, rp)
        T[idx] = (__bf16)((float)T[idx] + sc * (r * ap));
        apr *= a; rp *= ia;
      }
    }
    {
      float r = S[1][cc][ch], apr = A0B, rp = R0B;
      #pragma unroll 4
      for (int j = 31; j >= 0; --j) {
        int p = (cc << 5) + j;
        int idx = p * 32 + ch;
        float uu = (float)Y[idx];
        float ap = fmaxf(apr, 1e-20f);
        STEP(r, uu, apr, rp)
        float y = (float)T[idx] + sc * (r * ap) + dd * uu;
        float g = (float)gb[(size_t)p * 512];
        yb[(size_t)p * 512] = (__bf16)(y * g);
        apr *= a; rp *= ia;
      }
    }
  }
  #undef STEP
  #undef BASES
}

// ---------------- mean over 1024 positions (bf16 in) -> (16, 512) fp32 ----------------
__global__ __launch_bounds__(64) void reduce_k(const __bf16* __restrict__ hn, float* __restrict__ out)
{
  int d = blockIdx.y * 64 + threadIdx.x;
  int b = blockIdx.x;
  const __bf16* p = hn + ((size_t)b << 19) + d;
  float s0 = 0.f, s1 = 0.f, s2 = 0.f, s3 = 0.f;
  for (int t = 0; t < 1024; t += 4) {
    s0 += (float)p[(size_t)(t+0) << 9];
    s1 += (float)p[(size_t)(t+1) << 9];
    s2 += (float)p[(size_t)(t+2) << 9];
    s3 += (float)p[(size_t)(t+3) << 9];
  }
  out[b * 512 + d] = (s0 + s1 + s2 + s3) * (1.f / 1024.f);
}

extern "C" void kernel_launch(void* const* d_in, const int* in_sizes, int n_in,
                              void* d_out, int out_size, void* d_ws, size_t ws_size,
                              hipStream_t stream)
{
  const float* tokens = (const float*)d_in[0];
  const float* in_w   = (const float*)d_in[1];
  const float* in_b   = (const float*)d_in[2];
  const float* nw     = (const float*)d_in[3];
  const float* nb     = (const float*)d_in[4];
  const float* iw     = (const float*)d_in[5];
  const float* ib     = (const float*)d_in[6];
  const float* cw     = (const float*)d_in[7];
  const float* cb     = (const float*)d_in[8];
  const float* al     = (const float*)d_in[9];
  const float* bbv    = (const float*)d_in[10];
  const float* ccv    = (const float*)d_in[11];
  const float* ddv    = (const float*)d_in[12];
  const float* ow     = (const float*)d_in[13];
  const float* obv    = (const float*)d_in[14];
  const float* onw    = (const float*)d_in[15];
  const float* onb    = (const float*)d_in[16];

  // workspace layout (~132 MB):
  float*  x     = (float*)d_ws;                      // fp32 residual (33.5 MB)
  __bf16* hy16  = (__bf16*)(x + PP);                 // bf16 h / yg / final-ln (16.8 MB)
  __bf16* xin16 = hy16 + PP;                         // bf16 x_in (16.8 MB)
  __bf16* g16   = xin16 + PP;                        // bf16 gate (16.8 MB)
  __bf16* iwT   = g16 + PP;                          // 4x(1024x512) bf16 (4.2 MB)
  __bf16* owT   = iwT + (size_t)4 * 1024 * 512;      // 4x(512x512) bf16 (2.1 MB)
  __bf16* tb16  = owT + (size_t)4 * 512 * 512;       // tokens bf16 (25.2 MB)
  __bf16* inwT  = xin16;                             // in_proj_w^T bf16 (pre-loop alias)

  // --- weight/input conversion (once per launch) ---
  cvt_k<<<6144, 256, 0, stream>>>(tokens, tb16);
  tr_k<<<dim3(16, 24, 1), 256, 0, stream>>>(in_w, inwT, 768, 512, 0, 0);
  tr_k<<<dim3(32, 16, 4), 256, 0, stream>>>(iw, iwT, 512, 1024, (size_t)512*1024, (size_t)1024*512);
  tr_k<<<dim3(16, 16, 4), 256, 0, stream>>>(ow, owT, 512, 512, (size_t)512*512, (size_t)512*512);

  // x = tokens @ in_proj_w + b   (grid: M-tiles fastest)
  gemm_bf_k<<<dim3(128, 4), 256, 0, stream>>>(tb16, inwT, in_b, nullptr, x, nullptr, nullptr,
                                              512, 768, 0);

  for (int i = 0; i < 4; ++i) {
    ln_k<<<4096, 256, 0, stream>>>(x, nw + i*512, nb + i*512, hy16);
    gemm_bf_k<<<dim3(128, 8), 256, 0, stream>>>(hy16, iwT + (size_t)i*1024*512, ib + i*1024,
                                                nullptr, nullptr, g16, xin16, 1024, 512, 1);
    scan2d_k<<<dim3(16, 16), 512, 0, stream>>>(xin16, cw + i*9*512, cb + i*512,
                                               al + i*512, bbv + i*512, ccv + i*512,
                                               ddv + i*512, g16, hy16);
    gemm_bf_k<<<dim3(128, 4), 256, 0, stream>>>(hy16, owT + (size_t)i*512*512, obv + i*512,
                                                x, x, nullptr, nullptr, 512, 512, 2);
  }

  ln_k<<<4096, 256, 0, stream>>>(x, onw, onb, hy16);
  reduce_k<<<dim3(16, 8), 64, 0, stream>>>(hy16, (float*)d_out);
}